// Round 1
// baseline (6505.547 us; speedup 1.0000x reference)
//
#include <hip/hip_runtime.h>
#include <math.h>

// Problem constants (match reference)
#define R_REL 2
#define H_HEADS 2
#define IN_DIM 128
#define HID_DIM 64
#define OUT_DIM 64
// H*HID = H*OUT = 128 columns in both layers' feat
#define FCOLS 128

__device__ __forceinline__ void atomicMaxF(float* addr, float val) {
    // monotonic-bits trick; addr initialized to -inf
    if (val >= 0.f) atomicMax(reinterpret_cast<int*>(addr), __float_as_int(val));
    else atomicMin(reinterpret_cast<unsigned int*>(addr), __float_as_uint(val));
}

// ---------------------------------------------------------------------------
// feat = X (n x K) @ W (K x 128), plus el[n][h] = dot(feat[n,h,:], al[h,:]),
// er likewise. al/ar passed as flat 128 floats (H*D).
// Block: 256 threads, 64 nodes per block. W staged in LDS.
// Thread t: cols cg*4..cg*4+3 (cg = t&31), nodes n0..n0+7 (n0 from t>>5).
// ---------------------------------------------------------------------------
template <int K>
__launch_bounds__(256)
__global__ void feat_gemm_kernel(const float* __restrict__ X,
                                 const float* __restrict__ W,
                                 const float* __restrict__ alv,
                                 const float* __restrict__ arv,
                                 float* __restrict__ feat,
                                 float* __restrict__ el,
                                 float* __restrict__ er,
                                 int n) {
    __shared__ float4 Wl4[K * 32];
    const int tid = threadIdx.x;
    const float4* W4 = reinterpret_cast<const float4*>(W);
    for (int i = tid; i < K * 32; i += 256) Wl4[i] = W4[i];
    __syncthreads();

    const int cg = tid & 31;   // column group (4 cols)
    const int ng = tid >> 5;   // node subgroup 0..7
    const int n0 = blockIdx.x * 64 + ng * 8;

    float4 acc[8];
#pragma unroll
    for (int i = 0; i < 8; i++) acc[i] = make_float4(0.f, 0.f, 0.f, 0.f);

    const int KV = K / 4;
    const float4* X4 = reinterpret_cast<const float4*>(X);
    // clamped row pointers (writes are guarded later)
    const float4* xrow[8];
#pragma unroll
    for (int i = 0; i < 8; i++) {
        int nn = n0 + i;
        int nc = nn < n ? nn : (n - 1);
        xrow[i] = X4 + (size_t)nc * KV;
    }

    for (int k4 = 0; k4 < KV; ++k4) {
        float4 xv[8];
#pragma unroll
        for (int i = 0; i < 8; i++) xv[i] = xrow[i][k4];
#pragma unroll
        for (int j = 0; j < 4; j++) {
            float4 wv = Wl4[(k4 * 4 + j) * 32 + cg];
#pragma unroll
            for (int i = 0; i < 8; i++) {
                float xs = (j == 0) ? xv[i].x : (j == 1) ? xv[i].y : (j == 2) ? xv[i].z : xv[i].w;
                acc[i].x = fmaf(xs, wv.x, acc[i].x);
                acc[i].y = fmaf(xs, wv.y, acc[i].y);
                acc[i].z = fmaf(xs, wv.z, acc[i].z);
                acc[i].w = fmaf(xs, wv.w, acc[i].w);
            }
        }
    }

    const float4 alq = reinterpret_cast<const float4*>(alv)[cg];
    const float4 arq = reinterpret_cast<const float4*>(arv)[cg];
    float4* F4 = reinterpret_cast<float4*>(feat);
#pragma unroll
    for (int i = 0; i < 8; i++) {
        int nn = n0 + i;
        float pel = acc[i].x * alq.x + acc[i].y * alq.y + acc[i].z * alq.z + acc[i].w * alq.w;
        float per = acc[i].x * arq.x + acc[i].y * arq.y + acc[i].z * arq.z + acc[i].w * arq.w;
        // reduce across the 16 lanes holding this node's head
#pragma unroll
        for (int msk = 8; msk >= 1; msk >>= 1) {
            pel += __shfl_xor(pel, msk);
            per += __shfl_xor(per, msk);
        }
        if (nn < n) {
            F4[(size_t)nn * 32 + cg] = acc[i];
            if ((cg & 15) == 0) {
                int h = cg >> 4;
                el[nn * 2 + h] = pel;
                er[nn * 2 + h] = per;
            }
        }
    }
}

// ---------------------------------------------------------------------------
__global__ void bias_init_kernel(float* __restrict__ hbuf,
                                 const float* __restrict__ ba,
                                 const float* __restrict__ bb,
                                 int total4) {  // total4 = N*32 float4s
    int i = blockIdx.x * blockDim.x + threadIdx.x;
    if (i >= total4) return;
    int c = i & 31;
    float4 a = reinterpret_cast<const float4*>(ba)[c];
    float4 b = reinterpret_cast<const float4*>(bb)[c];
    reinterpret_cast<float4*>(hbuf)[i] = make_float4(a.x + b.x, a.y + b.y, a.z + b.z, a.w + b.w);
}

__global__ void minit_kernel(float* __restrict__ m, float* __restrict__ den, int n2) {
    int i = blockIdx.x * blockDim.x + threadIdx.x;
    if (i >= n2) return;
    m[i] = __int_as_float(0xFF800000);  // -inf
    den[i] = 0.f;
}

// ---------------------------------------------------------------------------
__global__ void edge_scores_max_kernel(const int* __restrict__ src, const int* __restrict__ dst,
                                       const float* __restrict__ el, const float* __restrict__ er,
                                       float* __restrict__ sc, float* __restrict__ m, int E) {
    int e = blockIdx.x * blockDim.x + threadIdx.x;
    if (e >= E) return;
    int si = src[e], di = dst[e];
    float2 a = *reinterpret_cast<const float2*>(el + (size_t)si * 2);
    float2 b = *reinterpret_cast<const float2*>(er + (size_t)di * 2);
    float s0 = a.x + b.x; s0 = s0 > 0.f ? s0 : 0.2f * s0;
    float s1 = a.y + b.y; s1 = s1 > 0.f ? s1 : 0.2f * s1;
    *reinterpret_cast<float2*>(sc + (size_t)e * 2) = make_float2(s0, s1);
    atomicMaxF(m + (size_t)di * 2, s0);
    atomicMaxF(m + (size_t)di * 2 + 1, s1);
}

__global__ void edge_exp_den_kernel(const int* __restrict__ dst, const float* __restrict__ m,
                                    float* __restrict__ sc, float* __restrict__ den, int E) {
    int e = blockIdx.x * blockDim.x + threadIdx.x;
    if (e >= E) return;
    int di = dst[e];
    float2 mm = *reinterpret_cast<const float2*>(m + (size_t)di * 2);
    float2 s = *reinterpret_cast<const float2*>(sc + (size_t)e * 2);
    float e0 = __expf(s.x - mm.x);
    float e1 = __expf(s.y - mm.y);
    *reinterpret_cast<float2*>(sc + (size_t)e * 2) = make_float2(e0, e1);
    atomicAdd(den + (size_t)di * 2, e0);
    atomicAdd(den + (size_t)di * 2 + 1, e1);
}

// 32 lanes per edge: each lane handles 4 consecutive feat columns.
__launch_bounds__(256)
__global__ void edge_aggregate_kernel(const int* __restrict__ src, const int* __restrict__ dst,
                                      const float* __restrict__ sc, const float* __restrict__ den,
                                      const float* __restrict__ feat, float* __restrict__ hout,
                                      int E) {
    int e = blockIdx.x * 8 + (threadIdx.x >> 5);
    if (e >= E) return;
    int lane = threadIdx.x & 31;
    int si = src[e], di = dst[e];
    int h = lane >> 4;
    float alpha = sc[(size_t)e * 2 + h] / den[(size_t)di * 2 + h];
    float4 fv = reinterpret_cast<const float4*>(feat)[(size_t)si * 32 + lane];
    float* outp = hout + (size_t)di * 128 + lane * 4;
    atomicAdd(outp + 0, fv.x * alpha);
    atomicAdd(outp + 1, fv.y * alpha);
    atomicAdd(outp + 2, fv.z * alpha);
    atomicAdd(outp + 3, fv.w * alpha);
}

// ---------------------------------------------------------------------------
// Hout (n x 64) = [relu]( Hin (n x 128) @ Wl (128 x 64) + bl )
// Block 256: 16 nodes per block; thread = (node sub i in 0..3 via t>>6)*4, col t&63
// ---------------------------------------------------------------------------
template <bool RELU>
__launch_bounds__(256)
__global__ void linear_kernel(const float* __restrict__ Hin, const float* __restrict__ Wl,
                              const float* __restrict__ bl, float* __restrict__ Hout, int n) {
    int col = threadIdx.x & 63;
    int nbase = blockIdx.x * 16 + (threadIdx.x >> 6) * 4;
    float acc[4];
#pragma unroll
    for (int i = 0; i < 4; i++) acc[i] = bl[col];
    const float* h0 = Hin + (size_t)nbase * 128;
#pragma unroll 4
    for (int k = 0; k < 128; k++) {
        float w = Wl[k * 64 + col];
#pragma unroll
        for (int i = 0; i < 4; i++) {
            int nn = nbase + i;
            float x = (nn < n) ? h0[(size_t)i * 128 + k] : 0.f;
            acc[i] = fmaf(x, w, acc[i]);
        }
    }
#pragma unroll
    for (int i = 0; i < 4; i++) {
        int nn = nbase + i;
        if (nn < n) {
            float v = acc[i];
            if (RELU) v = fmaxf(v, 0.f);
            Hout[(size_t)nn * 64 + col] = v;
        }
    }
}

// ---------------------------------------------------------------------------
extern "C" void kernel_launch(void* const* d_in, const int* in_sizes, int n_in,
                              void* d_out, int out_size, void* d_ws, size_t ws_size,
                              hipStream_t stream) {
    const float* x    = (const float*)d_in[0];
    const int*   src  = (const int*)d_in[1];
    const int*   dst  = (const int*)d_in[2];
    const float* W0   = (const float*)d_in[3];
    const float* al0  = (const float*)d_in[4];
    const float* ar0  = (const float*)d_in[5];
    const float* b0   = (const float*)d_in[6];
    const float* W1   = (const float*)d_in[7];
    const float* al1  = (const float*)d_in[8];
    const float* ar1  = (const float*)d_in[9];
    const float* b1   = (const float*)d_in[10];
    const float* linW0 = (const float*)d_in[11];
    const float* linb0 = (const float*)d_in[12];
    const float* linW1 = (const float*)d_in[13];
    const float* linb1 = (const float*)d_in[14];
    float* out = (float*)d_out;

    const int N = in_sizes[0] / IN_DIM;
    const int E = in_sizes[1] / R_REL;

    // workspace layout (floats)
    float* ws   = (float*)d_ws;
    float* feat = ws;                       // N*128
    float* hbuf = feat + (size_t)N * 128;   // N*128  (h0 then h1)
    float* hmid = hbuf + (size_t)N * 128;   // N*64   (h)
    float* el   = hmid + (size_t)N * 64;    // N*2
    float* er   = el + (size_t)N * 2;       // N*2
    float* mseg = er + (size_t)N * 2;       // N*2
    float* den  = mseg + (size_t)N * 2;     // N*2
    float* sc   = den + (size_t)N * 2;      // E*2

    const int TB = 256;
    const int gemm_blocks = (N + 63) / 64;
    const int b4 = (N * 32 + TB - 1) / TB;
    const int bn2 = (N * 2 + TB - 1) / TB;
    const int be = (E + TB - 1) / TB;
    const int bagg = (E + 7) / 8;
    const int blin = (N + 15) / 16;

    // ---------------- layer 0 ----------------
    bias_init_kernel<<<b4, TB, 0, stream>>>(hbuf, b0, b0 + 128, N * 32);
    for (int r = 0; r < R_REL; r++) {
        const float* Wr = W0 + (size_t)r * IN_DIM * FCOLS;
        const float* alr = al0 + (size_t)r * FCOLS;
        const float* arr = ar0 + (size_t)r * FCOLS;
        const int* sr = src + (size_t)r * E;
        const int* dr = dst + (size_t)r * E;
        feat_gemm_kernel<IN_DIM><<<gemm_blocks, TB, 0, stream>>>(x, Wr, alr, arr, feat, el, er, N);
        minit_kernel<<<bn2, TB, 0, stream>>>(mseg, den, N * 2);
        edge_scores_max_kernel<<<be, TB, 0, stream>>>(sr, dr, el, er, sc, mseg, E);
        edge_exp_den_kernel<<<be, TB, 0, stream>>>(dr, mseg, sc, den, E);
        edge_aggregate_kernel<<<bagg, TB, 0, stream>>>(sr, dr, sc, den, feat, hbuf, E);
    }
    linear_kernel<true><<<blin, TB, 0, stream>>>(hbuf, linW0, linb0, hmid, N);

    // ---------------- layer 1 ----------------
    bias_init_kernel<<<b4, TB, 0, stream>>>(hbuf, b1, b1 + 128, N * 32);
    for (int r = 0; r < R_REL; r++) {
        const float* Wr = W1 + (size_t)r * HID_DIM * FCOLS;
        const float* alr = al1 + (size_t)r * FCOLS;
        const float* arr = ar1 + (size_t)r * FCOLS;
        const int* sr = src + (size_t)r * E;
        const int* dr = dst + (size_t)r * E;
        feat_gemm_kernel<HID_DIM><<<gemm_blocks, TB, 0, stream>>>(hmid, Wr, alr, arr, feat, el, er, N);
        minit_kernel<<<bn2, TB, 0, stream>>>(mseg, den, N * 2);
        edge_scores_max_kernel<<<be, TB, 0, stream>>>(sr, dr, el, er, sc, mseg, E);
        edge_exp_den_kernel<<<be, TB, 0, stream>>>(dr, mseg, sc, den, E);
        edge_aggregate_kernel<<<bagg, TB, 0, stream>>>(sr, dr, sc, den, feat, hbuf, E);
    }
    linear_kernel<false><<<blin, TB, 0, stream>>>(hbuf, linW1, linb1, out, N);
}

// Round 2
// 1229.730 us; speedup vs baseline: 5.2902x; 5.2902x over previous
//
#include <hip/hip_runtime.h>
#include <math.h>

// Problem constants (match reference)
#define R_REL 2
#define IN_DIM 128
#define HID_DIM 64
#define FCOLS 128

// ---------------------------------------------------------------------------
// feat = X (n x K) @ W (K x 128), plus el[n][h] = dot(feat[n,h,:], al[h,:]),
// er likewise. al/ar passed as flat 128 floats (H*D).
// ---------------------------------------------------------------------------
template <int K>
__launch_bounds__(256)
__global__ void feat_gemm_kernel(const float* __restrict__ X,
                                 const float* __restrict__ W,
                                 const float* __restrict__ alv,
                                 const float* __restrict__ arv,
                                 float* __restrict__ feat,
                                 float* __restrict__ el,
                                 float* __restrict__ er,
                                 int n) {
    __shared__ float4 Wl4[K * 32];
    const int tid = threadIdx.x;
    const float4* W4 = reinterpret_cast<const float4*>(W);
    for (int i = tid; i < K * 32; i += 256) Wl4[i] = W4[i];
    __syncthreads();

    const int cg = tid & 31;   // column group (4 cols)
    const int ng = tid >> 5;   // node subgroup 0..7
    const int n0 = blockIdx.x * 64 + ng * 8;

    float4 acc[8];
#pragma unroll
    for (int i = 0; i < 8; i++) acc[i] = make_float4(0.f, 0.f, 0.f, 0.f);

    const int KV = K / 4;
    const float4* X4 = reinterpret_cast<const float4*>(X);
    const float4* xrow[8];
#pragma unroll
    for (int i = 0; i < 8; i++) {
        int nn = n0 + i;
        int nc = nn < n ? nn : (n - 1);
        xrow[i] = X4 + (size_t)nc * KV;
    }

    for (int k4 = 0; k4 < KV; ++k4) {
        float4 xv[8];
#pragma unroll
        for (int i = 0; i < 8; i++) xv[i] = xrow[i][k4];
#pragma unroll
        for (int j = 0; j < 4; j++) {
            float4 wv = Wl4[(k4 * 4 + j) * 32 + cg];
#pragma unroll
            for (int i = 0; i < 8; i++) {
                float xs = (j == 0) ? xv[i].x : (j == 1) ? xv[i].y : (j == 2) ? xv[i].z : xv[i].w;
                acc[i].x = fmaf(xs, wv.x, acc[i].x);
                acc[i].y = fmaf(xs, wv.y, acc[i].y);
                acc[i].z = fmaf(xs, wv.z, acc[i].z);
                acc[i].w = fmaf(xs, wv.w, acc[i].w);
            }
        }
    }

    const float4 alq = reinterpret_cast<const float4*>(alv)[cg];
    const float4 arq = reinterpret_cast<const float4*>(arv)[cg];
    float4* F4 = reinterpret_cast<float4*>(feat);
#pragma unroll
    for (int i = 0; i < 8; i++) {
        int nn = n0 + i;
        float pel = acc[i].x * alq.x + acc[i].y * alq.y + acc[i].z * alq.z + acc[i].w * alq.w;
        float per = acc[i].x * arq.x + acc[i].y * arq.y + acc[i].z * arq.z + acc[i].w * arq.w;
#pragma unroll
        for (int msk = 8; msk >= 1; msk >>= 1) {
            pel += __shfl_xor(pel, msk);
            per += __shfl_xor(per, msk);
        }
        if (nn < n) {
            F4[(size_t)nn * 32 + cg] = acc[i];
            if ((cg & 15) == 0) {
                int h = cg >> 4;
                el[nn * 2 + h] = pel;
                er[nn * 2 + h] = per;
            }
        }
    }
}

// ---------------------------------------------------------------------------
// CSR build: counts -> exclusive scan -> fill (once per call, reused by both
// layers; R=2 relations).
// ---------------------------------------------------------------------------
__global__ void zero_counts_kernel(int* __restrict__ counts, int n) {
    int i = blockIdx.x * blockDim.x + threadIdx.x;
    if (i < n) counts[i] = 0;
}

__global__ void count_kernel(const int* __restrict__ dst, int* __restrict__ counts,
                             int E, int N) {
    int i = blockIdx.x * blockDim.x + threadIdx.x;
    if (i >= 2 * E) return;
    int r = (i >= E) ? 1 : 0;
    atomicAdd(&counts[r * N + dst[i]], 1);
}

#define SCAN_T 1024
__global__ void scan_kernel(const int* __restrict__ counts, int* __restrict__ ptr,
                            int* __restrict__ cursor, int N) {
    int r = blockIdx.x;
    const int* c = counts + (size_t)r * N;
    int* p = ptr + (size_t)r * (N + 1);
    int* cur = cursor + (size_t)r * N;
    int t = threadIdx.x;
    int chunk = (N + SCAN_T - 1) / SCAN_T;
    int i0 = t * chunk;
    int i1 = i0 + chunk; if (i1 > N) i1 = N;
    int ts = 0;
    for (int i = i0; i < i1; i++) ts += c[i];
    __shared__ int sd[SCAN_T];
    sd[t] = ts;
    __syncthreads();
    for (int off = 1; off < SCAN_T; off <<= 1) {
        int v = sd[t];
        int u = (t >= off) ? sd[t - off] : 0;
        __syncthreads();
        sd[t] = v + u;
        __syncthreads();
    }
    int run = sd[t] - ts;  // exclusive prefix of this thread's chunk
    for (int i = i0; i < i1; i++) {
        p[i] = run;
        cur[i] = run;
        run += c[i];
    }
    if (t == SCAN_T - 1) p[N] = sd[SCAN_T - 1];
}

__global__ void fill_kernel(const int* __restrict__ src, const int* __restrict__ dst,
                            int* __restrict__ cursor, int* __restrict__ csr_src,
                            int E, int N) {
    int i = blockIdx.x * blockDim.x + threadIdx.x;
    if (i >= 2 * E) return;
    int r = (i >= E) ? 1 : 0;
    int pos = atomicAdd(&cursor[r * N + dst[i]], 1);
    csr_src[(size_t)r * E + pos] = src[i];
}

// ---------------------------------------------------------------------------
// Owner-computes GAT aggregation: one 64-lane wave per destination node.
// Online (flash-style) softmax over chunks of <=64 in-edges; the per-edge
// feat row (512 B) is gathered coalesced, 2 floats per lane.
// FIRST: hout = bias(ba+bb) + agg ; else: hout += agg.
// ---------------------------------------------------------------------------
template <bool FIRST>
__launch_bounds__(256)
__global__ void gat_aggregate_kernel(const int* __restrict__ rowptr,
                                     const int* __restrict__ csrc,
                                     const float* __restrict__ el,
                                     const float* __restrict__ er,
                                     const float* __restrict__ feat,
                                     const float* __restrict__ ba,
                                     const float* __restrict__ bb,
                                     float* __restrict__ hout,
                                     int n) {
    int node = blockIdx.x * 4 + (threadIdx.x >> 6);
    if (node >= n) return;
    int lane = threadIdx.x & 63;
    int h = lane >> 5;  // lane covers cols 2*lane, 2*lane+1 ; head = lane>>5

    int rs = rowptr[node], re = rowptr[node + 1];
    float er0 = er[node * 2], er1 = er[node * 2 + 1];

    float2 acc = make_float2(0.f, 0.f);
    float m0 = -INFINITY, m1 = -INFINITY;
    float den0 = 0.f, den1 = 0.f;
    const float2* feat2 = reinterpret_cast<const float2*>(feat);

    for (int base = rs; base < re; base += 64) {
        int c = re - base; if (c > 64) c = 64;
        int msrc = 0;
        float s0 = -INFINITY, s1 = -INFINITY;
        if (lane < c) {
            msrc = csrc[base + lane];
            float2 a = *reinterpret_cast<const float2*>(el + (size_t)msrc * 2);
            s0 = a.x + er0; s0 = s0 > 0.f ? s0 : 0.2f * s0;
            s1 = a.y + er1; s1 = s1 > 0.f ? s1 : 0.2f * s1;
        }
        float c0 = s0, c1 = s1;
#pragma unroll
        for (int msk = 32; msk >= 1; msk >>= 1) {
            c0 = fmaxf(c0, __shfl_xor(c0, msk));
            c1 = fmaxf(c1, __shfl_xor(c1, msk));
        }
        float mn0 = fmaxf(m0, c0), mn1 = fmaxf(m1, c1);
        float sc0 = __expf(m0 - mn0), sc1 = __expf(m1 - mn1);
        float ex0 = (lane < c) ? __expf(s0 - mn0) : 0.f;
        float ex1 = (lane < c) ? __expf(s1 - mn1) : 0.f;
        float t0 = ex0, t1 = ex1;
#pragma unroll
        for (int msk = 32; msk >= 1; msk >>= 1) {
            t0 += __shfl_xor(t0, msk);
            t1 += __shfl_xor(t1, msk);
        }
        den0 = den0 * sc0 + t0;
        den1 = den1 * sc1 + t1;
        float sch = (h == 0) ? sc0 : sc1;
        acc.x *= sch;
        acc.y *= sch;
        for (int j = 0; j < c; ++j) {
            int sj = __shfl(msrc, j);
            float a0 = __shfl(ex0, j);
            float a1 = __shfl(ex1, j);
            float a = (h == 0) ? a0 : a1;
            float2 f = feat2[(size_t)sj * 64 + lane];
            acc.x = fmaf(a, f.x, acc.x);
            acc.y = fmaf(a, f.y, acc.y);
        }
        m0 = mn0;
        m1 = mn1;
    }

    float den = (h == 0) ? den0 : den1;
    float invd = (den > 0.f) ? 1.f / den : 0.f;
    float2* o2 = reinterpret_cast<float2*>(hout) + (size_t)node * 64 + lane;
    float2 o;
    if (FIRST) {
        const float2* ba2 = reinterpret_cast<const float2*>(ba);
        const float2* bb2 = reinterpret_cast<const float2*>(bb);
        float2 b1v = ba2[lane], b2v = bb2[lane];
        o.x = b1v.x + b2v.x + acc.x * invd;
        o.y = b1v.y + b2v.y + acc.y * invd;
    } else {
        o = *o2;
        o.x += acc.x * invd;
        o.y += acc.y * invd;
    }
    *o2 = o;
}

// ---------------------------------------------------------------------------
// Hout (n x 64) = [relu]( Hin (n x 128) @ Wl (128 x 64) + bl )
// ---------------------------------------------------------------------------
template <bool RELU>
__launch_bounds__(256)
__global__ void linear_kernel(const float* __restrict__ Hin, const float* __restrict__ Wl,
                              const float* __restrict__ bl, float* __restrict__ Hout, int n) {
    int col = threadIdx.x & 63;
    int nbase = blockIdx.x * 16 + (threadIdx.x >> 6) * 4;
    float acc[4];
#pragma unroll
    for (int i = 0; i < 4; i++) acc[i] = bl[col];
    const float* h0 = Hin + (size_t)nbase * 128;
#pragma unroll 4
    for (int k = 0; k < 128; k++) {
        float w = Wl[k * 64 + col];
#pragma unroll
        for (int i = 0; i < 4; i++) {
            int nn = nbase + i;
            float x = (nn < n) ? h0[(size_t)i * 128 + k] : 0.f;
            acc[i] = fmaf(x, w, acc[i]);
        }
    }
#pragma unroll
    for (int i = 0; i < 4; i++) {
        int nn = nbase + i;
        if (nn < n) {
            float v = acc[i];
            if (RELU) v = fmaxf(v, 0.f);
            Hout[(size_t)nn * 64 + col] = v;
        }
    }
}

// ---------------------------------------------------------------------------
extern "C" void kernel_launch(void* const* d_in, const int* in_sizes, int n_in,
                              void* d_out, int out_size, void* d_ws, size_t ws_size,
                              hipStream_t stream) {
    const float* x    = (const float*)d_in[0];
    const int*   src  = (const int*)d_in[1];
    const int*   dst  = (const int*)d_in[2];
    const float* W0   = (const float*)d_in[3];
    const float* al0  = (const float*)d_in[4];
    const float* ar0  = (const float*)d_in[5];
    const float* b0   = (const float*)d_in[6];
    const float* W1   = (const float*)d_in[7];
    const float* al1  = (const float*)d_in[8];
    const float* ar1  = (const float*)d_in[9];
    const float* b1   = (const float*)d_in[10];
    const float* linW0 = (const float*)d_in[11];
    const float* linb0 = (const float*)d_in[12];
    const float* linW1 = (const float*)d_in[13];
    const float* linb1 = (const float*)d_in[14];
    float* out = (float*)d_out;

    const int N = in_sizes[0] / IN_DIM;
    const int E = in_sizes[1] / R_REL;

    // workspace layout
    float* ws   = (float*)d_ws;
    float* feat = ws;                       // N*128
    float* hbuf = feat + (size_t)N * 128;   // N*128
    float* hmid = hbuf + (size_t)N * 128;   // N*64
    float* el   = hmid + (size_t)N * 64;    // N*2
    float* er   = el + (size_t)N * 2;       // N*2
    int* counts = (int*)(er + (size_t)N * 2);      // 2*N
    int* rowptr = counts + (size_t)2 * N;          // 2*(N+1)
    int* cursor = rowptr + (size_t)2 * (N + 1);    // 2*N
    int* csrsrc = cursor + (size_t)2 * N;          // 2*E

    const int TB = 256;
    const int gemm_blocks = (N + 63) / 64;
    const int bagg = (N + 3) / 4;
    const int blin = (N + 15) / 16;
    const int b2n = (2 * N + TB - 1) / TB;
    const int b2e = (2 * E + TB - 1) / TB;

    // ---------------- CSR build (once; shared by both layers) -------------
    zero_counts_kernel<<<b2n, TB, 0, stream>>>(counts, 2 * N);
    count_kernel<<<b2e, TB, 0, stream>>>(dst, counts, E, N);
    scan_kernel<<<2, SCAN_T, 0, stream>>>(counts, rowptr, cursor, N);
    fill_kernel<<<b2e, TB, 0, stream>>>(src, dst, cursor, csrsrc, E, N);

    // ---------------- layer 0 ----------------
    for (int r = 0; r < R_REL; r++) {
        const float* Wr  = W0 + (size_t)r * IN_DIM * FCOLS;
        const float* alr = al0 + (size_t)r * FCOLS;
        const float* arr = ar0 + (size_t)r * FCOLS;
        feat_gemm_kernel<IN_DIM><<<gemm_blocks, TB, 0, stream>>>(x, Wr, alr, arr, feat, el, er, N);
        if (r == 0)
            gat_aggregate_kernel<true><<<bagg, TB, 0, stream>>>(
                rowptr, csrsrc, el, er, feat, b0, b0 + 128, hbuf, N);
        else
            gat_aggregate_kernel<false><<<bagg, TB, 0, stream>>>(
                rowptr + (size_t)(N + 1), csrsrc + (size_t)E, el, er, feat,
                nullptr, nullptr, hbuf, N);
    }
    linear_kernel<true><<<blin, TB, 0, stream>>>(hbuf, linW0, linb0, hmid, N);

    // ---------------- layer 1 ----------------
    for (int r = 0; r < R_REL; r++) {
        const float* Wr  = W1 + (size_t)r * HID_DIM * FCOLS;
        const float* alr = al1 + (size_t)r * FCOLS;
        const float* arr = ar1 + (size_t)r * FCOLS;
        feat_gemm_kernel<HID_DIM><<<gemm_blocks, TB, 0, stream>>>(hmid, Wr, alr, arr, feat, el, er, N);
        if (r == 0)
            gat_aggregate_kernel<true><<<bagg, TB, 0, stream>>>(
                rowptr, csrsrc, el, er, feat, b1, b1 + 128, hbuf, N);
        else
            gat_aggregate_kernel<false><<<bagg, TB, 0, stream>>>(
                rowptr + (size_t)(N + 1), csrsrc + (size_t)E, el, er, feat,
                nullptr, nullptr, hbuf, N);
    }
    linear_kernel<false><<<blin, TB, 0, stream>>>(hbuf, linW1, linb1, out, N);
}

// Round 3
// 1019.518 us; speedup vs baseline: 6.3810x; 1.2062x over previous
//
#include <hip/hip_runtime.h>
#include <math.h>

// Problem constants (match reference)
#define R_REL 2
#define IN_DIM 128
#define HID_DIM 64
#define FCOLS 128

// ---------------------------------------------------------------------------
// feat = X (n x K) @ W (K x 128), plus el[n][h] = dot(feat[n,h,:], al[h,:]),
// er likewise. al/ar passed as flat 128 floats (H*D).
// ---------------------------------------------------------------------------
template <int K>
__launch_bounds__(256)
__global__ void feat_gemm_kernel(const float* __restrict__ X,
                                 const float* __restrict__ W,
                                 const float* __restrict__ alv,
                                 const float* __restrict__ arv,
                                 float* __restrict__ feat,
                                 float* __restrict__ el,
                                 float* __restrict__ er,
                                 int n) {
    __shared__ float4 Wl4[K * 32];
    const int tid = threadIdx.x;
    const float4* W4 = reinterpret_cast<const float4*>(W);
    for (int i = tid; i < K * 32; i += 256) Wl4[i] = W4[i];
    __syncthreads();

    const int cg = tid & 31;   // column group (4 cols)
    const int ng = tid >> 5;   // node subgroup 0..7
    const int n0 = blockIdx.x * 64 + ng * 8;

    float4 acc[8];
#pragma unroll
    for (int i = 0; i < 8; i++) acc[i] = make_float4(0.f, 0.f, 0.f, 0.f);

    const int KV = K / 4;
    const float4* X4 = reinterpret_cast<const float4*>(X);
    const float4* xrow[8];
#pragma unroll
    for (int i = 0; i < 8; i++) {
        int nn = n0 + i;
        int nc = nn < n ? nn : (n - 1);
        xrow[i] = X4 + (size_t)nc * KV;
    }

    for (int k4 = 0; k4 < KV; ++k4) {
        float4 xv[8];
#pragma unroll
        for (int i = 0; i < 8; i++) xv[i] = xrow[i][k4];
#pragma unroll
        for (int j = 0; j < 4; j++) {
            float4 wv = Wl4[(k4 * 4 + j) * 32 + cg];
#pragma unroll
            for (int i = 0; i < 8; i++) {
                float xs = (j == 0) ? xv[i].x : (j == 1) ? xv[i].y : (j == 2) ? xv[i].z : xv[i].w;
                acc[i].x = fmaf(xs, wv.x, acc[i].x);
                acc[i].y = fmaf(xs, wv.y, acc[i].y);
                acc[i].z = fmaf(xs, wv.z, acc[i].z);
                acc[i].w = fmaf(xs, wv.w, acc[i].w);
            }
        }
    }

    const float4 alq = reinterpret_cast<const float4*>(alv)[cg];
    const float4 arq = reinterpret_cast<const float4*>(arv)[cg];
    float4* F4 = reinterpret_cast<float4*>(feat);
#pragma unroll
    for (int i = 0; i < 8; i++) {
        int nn = n0 + i;
        float pel = acc[i].x * alq.x + acc[i].y * alq.y + acc[i].z * alq.z + acc[i].w * alq.w;
        float per = acc[i].x * arq.x + acc[i].y * arq.y + acc[i].z * arq.z + acc[i].w * arq.w;
#pragma unroll
        for (int msk = 8; msk >= 1; msk >>= 1) {
            pel += __shfl_xor(pel, msk);
            per += __shfl_xor(per, msk);
        }
        if (nn < n) {
            F4[(size_t)nn * 32 + cg] = acc[i];
            if ((cg & 15) == 0) {
                int h = cg >> 4;
                el[nn * 2 + h] = pel;
                er[nn * 2 + h] = per;
            }
        }
    }
}

// ---------------------------------------------------------------------------
// CSR build over the CONCATENATED relations: counts[2N] -> global exclusive
// scan S[2N+1] -> fill. Relation r's node i spans S[r*N+i] .. S[r*N+i+1] in
// the global csrsrc[2E] array (relation 1 lands at +E automatically).
// ---------------------------------------------------------------------------
__global__ void zero_counts_kernel(int* __restrict__ counts, int n) {
    int i = blockIdx.x * blockDim.x + threadIdx.x;
    if (i < n) counts[i] = 0;
}

__global__ void count_kernel(const int* __restrict__ dst, int* __restrict__ counts,
                             int E, int N) {
    int i = blockIdx.x * blockDim.x + threadIdx.x;
    if (i >= 2 * E) return;
    int r = (i >= E) ? 1 : 0;
    atomicAdd(&counts[r * N + dst[i]], 1);
}

// 3-phase scan, CHUNK = 2048 elements per 256-thread block (8/thread).
#define SCAN_CHUNK 2048
#define SCAN_BT 256

__global__ void scan_blocksum_kernel(const int* __restrict__ counts,
                                     int* __restrict__ bsum, int n) {
    int b = blockIdx.x, t = threadIdx.x;
    int base = b * SCAN_CHUNK + t * 8;
    int s = 0;
#pragma unroll
    for (int j = 0; j < 8; j++) {
        int i = base + j;
        if (i < n) s += counts[i];
    }
    __shared__ int sd[SCAN_BT];
    sd[t] = s;
    __syncthreads();
    for (int off = SCAN_BT / 2; off > 0; off >>= 1) {
        if (t < off) sd[t] += sd[t + off];
        __syncthreads();
    }
    if (t == 0) bsum[b] = sd[0];
}

// single block: exclusive-scan bsum[0..B), write total to S[n].
__global__ void scan_bsum_kernel(int* __restrict__ bsum, int* __restrict__ S,
                                 int B, int n) {
    __shared__ int sd[1024];
    int t = threadIdx.x;
    int v = (t < B) ? bsum[t] : 0;
    sd[t] = v;
    __syncthreads();
    for (int off = 1; off < 1024; off <<= 1) {
        int u = (t >= off) ? sd[t - off] : 0;
        __syncthreads();
        sd[t] = sd[t] + u;
        __syncthreads();
    }
    if (t < B) bsum[t] = sd[t] - v;         // exclusive
    if (t == 1023) S[n] = sd[1023];          // grand total
}

__global__ void scan_write_kernel(const int* __restrict__ counts,
                                  const int* __restrict__ bsum,
                                  int* __restrict__ S, int* __restrict__ cursor,
                                  int n) {
    int b = blockIdx.x, t = threadIdx.x;
    int base = b * SCAN_CHUNK + t * 8;
    int v[8];
    int s = 0;
#pragma unroll
    for (int j = 0; j < 8; j++) {
        int i = base + j;
        v[j] = (i < n) ? counts[i] : 0;
        s += v[j];
    }
    __shared__ int sd[SCAN_BT];
    sd[t] = s;
    __syncthreads();
    for (int off = 1; off < SCAN_BT; off <<= 1) {
        int u = (t >= off) ? sd[t - off] : 0;
        __syncthreads();
        sd[t] = sd[t] + u;
        __syncthreads();
    }
    int run = bsum[b] + sd[t] - s;  // exclusive prefix for this thread's 8
#pragma unroll
    for (int j = 0; j < 8; j++) {
        int i = base + j;
        if (i < n) {
            S[i] = run;
            cursor[i] = run;
            run += v[j];
        }
    }
}

__global__ void fill_kernel(const int* __restrict__ src, const int* __restrict__ dst,
                            int* __restrict__ cursor, int* __restrict__ csr_src,
                            int E, int N) {
    int i = blockIdx.x * blockDim.x + threadIdx.x;
    if (i >= 2 * E) return;
    int r = (i >= E) ? 1 : 0;
    int pos = atomicAdd(&cursor[r * N + dst[i]], 1);
    csr_src[pos] = src[i];
}

// ---------------------------------------------------------------------------
// Owner-computes GAT aggregation: one 64-lane wave per destination node.
// Online (flash-style) softmax over chunks of <=64 in-edges; per-edge feat row
// (512 B) gathered coalesced, 2 floats per lane.
// FIRST: hout = bias(ba+bb) + agg ; else: hout += agg.
// ---------------------------------------------------------------------------
template <bool FIRST>
__launch_bounds__(256)
__global__ void gat_aggregate_kernel(const int* __restrict__ rowptr,
                                     const int* __restrict__ csrc,
                                     const float* __restrict__ el,
                                     const float* __restrict__ er,
                                     const float* __restrict__ feat,
                                     const float* __restrict__ ba,
                                     const float* __restrict__ bb,
                                     float* __restrict__ hout,
                                     int n) {
    int node = blockIdx.x * 4 + (threadIdx.x >> 6);
    if (node >= n) return;
    int lane = threadIdx.x & 63;
    int h = lane >> 5;

    int rs = rowptr[node], re = rowptr[node + 1];
    float er0 = er[node * 2], er1 = er[node * 2 + 1];

    float2 acc = make_float2(0.f, 0.f);
    float m0 = -INFINITY, m1 = -INFINITY;
    float den0 = 0.f, den1 = 0.f;
    const float2* feat2 = reinterpret_cast<const float2*>(feat);

    for (int base = rs; base < re; base += 64) {
        int c = re - base; if (c > 64) c = 64;
        int msrc = 0;
        float s0 = -INFINITY, s1 = -INFINITY;
        if (lane < c) {
            msrc = csrc[base + lane];
            float2 a = *reinterpret_cast<const float2*>(el + (size_t)msrc * 2);
            s0 = a.x + er0; s0 = s0 > 0.f ? s0 : 0.2f * s0;
            s1 = a.y + er1; s1 = s1 > 0.f ? s1 : 0.2f * s1;
        }
        float c0 = s0, c1 = s1;
#pragma unroll
        for (int msk = 32; msk >= 1; msk >>= 1) {
            c0 = fmaxf(c0, __shfl_xor(c0, msk));
            c1 = fmaxf(c1, __shfl_xor(c1, msk));
        }
        float mn0 = fmaxf(m0, c0), mn1 = fmaxf(m1, c1);
        float sc0 = __expf(m0 - mn0), sc1 = __expf(m1 - mn1);
        float ex0 = (lane < c) ? __expf(s0 - mn0) : 0.f;
        float ex1 = (lane < c) ? __expf(s1 - mn1) : 0.f;
        float t0 = ex0, t1 = ex1;
#pragma unroll
        for (int msk = 32; msk >= 1; msk >>= 1) {
            t0 += __shfl_xor(t0, msk);
            t1 += __shfl_xor(t1, msk);
        }
        den0 = den0 * sc0 + t0;
        den1 = den1 * sc1 + t1;
        float sch = (h == 0) ? sc0 : sc1;
        acc.x *= sch;
        acc.y *= sch;
        for (int j = 0; j < c; ++j) {
            int sj = __shfl(msrc, j);
            float a0 = __shfl(ex0, j);
            float a1 = __shfl(ex1, j);
            float a = (h == 0) ? a0 : a1;
            float2 f = feat2[(size_t)sj * 64 + lane];
            acc.x = fmaf(a, f.x, acc.x);
            acc.y = fmaf(a, f.y, acc.y);
        }
        m0 = mn0;
        m1 = mn1;
    }

    float den = (h == 0) ? den0 : den1;
    float invd = (den > 0.f) ? 1.f / den : 0.f;
    float2* o2 = reinterpret_cast<float2*>(hout) + (size_t)node * 64 + lane;
    float2 o;
    if (FIRST) {
        const float2* ba2 = reinterpret_cast<const float2*>(ba);
        const float2* bb2 = reinterpret_cast<const float2*>(bb);
        float2 b1v = ba2[lane], b2v = bb2[lane];
        o.x = b1v.x + b2v.x + acc.x * invd;
        o.y = b1v.y + b2v.y + acc.y * invd;
    } else {
        o = *o2;
        o.x += acc.x * invd;
        o.y += acc.y * invd;
    }
    *o2 = o;
}

// ---------------------------------------------------------------------------
// Hout (n x 64) = [relu]( Hin (n x 128) @ Wl (128 x 64) + bl )
// ---------------------------------------------------------------------------
template <bool RELU>
__launch_bounds__(256)
__global__ void linear_kernel(const float* __restrict__ Hin, const float* __restrict__ Wl,
                              const float* __restrict__ bl, float* __restrict__ Hout, int n) {
    int col = threadIdx.x & 63;
    int nbase = blockIdx.x * 16 + (threadIdx.x >> 6) * 4;
    float acc[4];
#pragma unroll
    for (int i = 0; i < 4; i++) acc[i] = bl[col];
    const float* h0 = Hin + (size_t)nbase * 128;
#pragma unroll 4
    for (int k = 0; k < 128; k++) {
        float w = Wl[k * 64 + col];
#pragma unroll
        for (int i = 0; i < 4; i++) {
            int nn = nbase + i;
            float x = (nn < n) ? h0[(size_t)i * 128 + k] : 0.f;
            acc[i] = fmaf(x, w, acc[i]);
        }
    }
#pragma unroll
    for (int i = 0; i < 4; i++) {
        int nn = nbase + i;
        if (nn < n) {
            float v = acc[i];
            if (RELU) v = fmaxf(v, 0.f);
            Hout[(size_t)nn * 64 + col] = v;
        }
    }
}

// ---------------------------------------------------------------------------
extern "C" void kernel_launch(void* const* d_in, const int* in_sizes, int n_in,
                              void* d_out, int out_size, void* d_ws, size_t ws_size,
                              hipStream_t stream) {
    const float* x    = (const float*)d_in[0];
    const int*   src  = (const int*)d_in[1];
    const int*   dst  = (const int*)d_in[2];
    const float* W0   = (const float*)d_in[3];
    const float* al0  = (const float*)d_in[4];
    const float* ar0  = (const float*)d_in[5];
    const float* b0   = (const float*)d_in[6];
    const float* W1   = (const float*)d_in[7];
    const float* al1  = (const float*)d_in[8];
    const float* ar1  = (const float*)d_in[9];
    const float* b1   = (const float*)d_in[10];
    const float* linW0 = (const float*)d_in[11];
    const float* linb0 = (const float*)d_in[12];
    const float* linW1 = (const float*)d_in[13];
    const float* linb1 = (const float*)d_in[14];
    float* out = (float*)d_out;

    const int N = in_sizes[0] / IN_DIM;
    const int E = in_sizes[1] / R_REL;
    const int n2 = 2 * N;

    // workspace layout
    float* ws   = (float*)d_ws;
    float* feat = ws;                       // N*128
    float* hbuf = feat + (size_t)N * 128;   // N*128
    float* hmid = hbuf + (size_t)N * 128;   // N*64
    float* el   = hmid + (size_t)N * 64;    // N*2
    float* er   = el + (size_t)N * 2;       // N*2
    int* counts = (int*)(er + (size_t)N * 2);      // 2N
    int* S      = counts + (size_t)n2;             // 2N+1 (global rowptr)
    int* cursor = S + (size_t)(n2 + 1);            // 2N
    int* bsum   = cursor + (size_t)n2;             // up to 1024
    int* csrsrc = bsum + 1024;                     // 2E

    const int TB = 256;
    const int gemm_blocks = (N + 63) / 64;
    const int bagg = (N + 3) / 4;
    const int blin = (N + 15) / 16;
    const int b2n = (n2 + TB - 1) / TB;
    const int b2e = (2 * E + TB - 1) / TB;
    const int bscan = (n2 + SCAN_CHUNK - 1) / SCAN_CHUNK;  // ~98

    // ---------------- CSR build (once; shared by both layers) -------------
    zero_counts_kernel<<<b2n, TB, 0, stream>>>(counts, n2);
    count_kernel<<<b2e, TB, 0, stream>>>(dst, counts, E, N);
    scan_blocksum_kernel<<<bscan, SCAN_BT, 0, stream>>>(counts, bsum, n2);
    scan_bsum_kernel<<<1, 1024, 0, stream>>>(bsum, S, bscan, n2);
    scan_write_kernel<<<bscan, SCAN_BT, 0, stream>>>(counts, bsum, S, cursor, n2);
    fill_kernel<<<b2e, TB, 0, stream>>>(src, dst, cursor, csrsrc, E, N);

    // ---------------- layer 0 ----------------
    for (int r = 0; r < R_REL; r++) {
        const float* Wr  = W0 + (size_t)r * IN_DIM * FCOLS;
        const float* alr = al0 + (size_t)r * FCOLS;
        const float* arr = ar0 + (size_t)r * FCOLS;
        feat_gemm_kernel<IN_DIM><<<gemm_blocks, TB, 0, stream>>>(x, Wr, alr, arr, feat, el, er, N);
        if (r == 0)
            gat_aggregate_kernel<true><<<bagg, TB, 0, stream>>>(
                S, csrsrc, el, er, feat, b0, b0 + 128, hbuf, N);
        else
            gat_aggregate_kernel<false><<<bagg, TB, 0, stream>>>(
                S + N, csrsrc, el, er, feat, nullptr, nullptr, hbuf, N);
    }
    linear_kernel<true><<<blin, TB, 0, stream>>>(hbuf, linW0, linb0, hmid, N);

    // ---------------- layer 1 ----------------
    for (int r = 0; r < R_REL; r++) {
        const float* Wr  = W1 + (size_t)r * HID_DIM * FCOLS;
        const float* alr = al1 + (size_t)r * FCOLS;
        const float* arr = ar1 + (size_t)r * FCOLS;
        feat_gemm_kernel<HID_DIM><<<gemm_blocks, TB, 0, stream>>>(hmid, Wr, alr, arr, feat, el, er, N);
        if (r == 0)
            gat_aggregate_kernel<true><<<bagg, TB, 0, stream>>>(
                S, csrsrc, el, er, feat, b1, b1 + 128, hbuf, N);
        else
            gat_aggregate_kernel<false><<<bagg, TB, 0, stream>>>(
                S + N, csrsrc, el, er, feat, nullptr, nullptr, hbuf, N);
    }
    linear_kernel<false><<<blin, TB, 0, stream>>>(hbuf, linW1, linb1, out, N);
}

// Round 4
// 858.315 us; speedup vs baseline: 7.5794x; 1.1878x over previous
//
#include <hip/hip_runtime.h>
#include <math.h>

// Problem constants (match reference)
#define R_REL 2
#define IN_DIM 128
#define HID_DIM 64
#define FCOLS 128

// ---------------------------------------------------------------------------
// feat = X (n x K) @ W (K x 128), plus el[n][h] = dot(feat[n,h,:], al[h,:]),
// er likewise. al/ar passed as flat 128 floats (H*D).
// ---------------------------------------------------------------------------
template <int K>
__launch_bounds__(256)
__global__ void feat_gemm_kernel(const float* __restrict__ X,
                                 const float* __restrict__ W,
                                 const float* __restrict__ alv,
                                 const float* __restrict__ arv,
                                 float* __restrict__ feat,
                                 float* __restrict__ el,
                                 float* __restrict__ er,
                                 int n) {
    __shared__ float4 Wl4[K * 32];
    const int tid = threadIdx.x;
    const float4* W4 = reinterpret_cast<const float4*>(W);
    for (int i = tid; i < K * 32; i += 256) Wl4[i] = W4[i];
    __syncthreads();

    const int cg = tid & 31;   // column group (4 cols)
    const int ng = tid >> 5;   // node subgroup 0..7
    const int n0 = blockIdx.x * 64 + ng * 8;

    float4 acc[8];
#pragma unroll
    for (int i = 0; i < 8; i++) acc[i] = make_float4(0.f, 0.f, 0.f, 0.f);

    const int KV = K / 4;
    const float4* X4 = reinterpret_cast<const float4*>(X);
    const float4* xrow[8];
#pragma unroll
    for (int i = 0; i < 8; i++) {
        int nn = n0 + i;
        int nc = nn < n ? nn : (n - 1);
        xrow[i] = X4 + (size_t)nc * KV;
    }

    for (int k4 = 0; k4 < KV; ++k4) {
        float4 xv[8];
#pragma unroll
        for (int i = 0; i < 8; i++) xv[i] = xrow[i][k4];
#pragma unroll
        for (int j = 0; j < 4; j++) {
            float4 wv = Wl4[(k4 * 4 + j) * 32 + cg];
#pragma unroll
            for (int i = 0; i < 8; i++) {
                float xs = (j == 0) ? xv[i].x : (j == 1) ? xv[i].y : (j == 2) ? xv[i].z : xv[i].w;
                acc[i].x = fmaf(xs, wv.x, acc[i].x);
                acc[i].y = fmaf(xs, wv.y, acc[i].y);
                acc[i].z = fmaf(xs, wv.z, acc[i].z);
                acc[i].w = fmaf(xs, wv.w, acc[i].w);
            }
        }
    }

    const float4 alq = reinterpret_cast<const float4*>(alv)[cg];
    const float4 arq = reinterpret_cast<const float4*>(arv)[cg];
    float4* F4 = reinterpret_cast<float4*>(feat);
#pragma unroll
    for (int i = 0; i < 8; i++) {
        int nn = n0 + i;
        float pel = acc[i].x * alq.x + acc[i].y * alq.y + acc[i].z * alq.z + acc[i].w * alq.w;
        float per = acc[i].x * arq.x + acc[i].y * arq.y + acc[i].z * arq.z + acc[i].w * arq.w;
#pragma unroll
        for (int msk = 8; msk >= 1; msk >>= 1) {
            pel += __shfl_xor(pel, msk);
            per += __shfl_xor(per, msk);
        }
        if (nn < n) {
            F4[(size_t)nn * 32 + cg] = acc[i];
            if ((cg & 15) == 0) {
                int h = cg >> 4;
                el[nn * 2 + h] = pel;
                er[nn * 2 + h] = per;
            }
        }
    }
}

// ---------------------------------------------------------------------------
// CSR build over the CONCATENATED relations: counts[2N] -> global exclusive
// scan S[2N+1] -> fill.
// ---------------------------------------------------------------------------
__global__ void zero_counts_kernel(int* __restrict__ counts, int n) {
    int i = blockIdx.x * blockDim.x + threadIdx.x;
    if (i < n) counts[i] = 0;
}

__global__ void count_kernel(const int* __restrict__ dst, int* __restrict__ counts,
                             int E, int N) {
    int i = blockIdx.x * blockDim.x + threadIdx.x;
    if (i >= 2 * E) return;
    int r = (i >= E) ? 1 : 0;
    atomicAdd(&counts[r * N + dst[i]], 1);
}

// 3-phase scan, CHUNK = 2048 elements per 256-thread block (8/thread).
#define SCAN_CHUNK 2048
#define SCAN_BT 256

__global__ void scan_blocksum_kernel(const int* __restrict__ counts,
                                     int* __restrict__ bsum, int n) {
    int b = blockIdx.x, t = threadIdx.x;
    int base = b * SCAN_CHUNK + t * 8;
    int s = 0;
#pragma unroll
    for (int j = 0; j < 8; j++) {
        int i = base + j;
        if (i < n) s += counts[i];
    }
    __shared__ int sd[SCAN_BT];
    sd[t] = s;
    __syncthreads();
    for (int off = SCAN_BT / 2; off > 0; off >>= 1) {
        if (t < off) sd[t] += sd[t + off];
        __syncthreads();
    }
    if (t == 0) bsum[b] = sd[0];
}

__global__ void scan_bsum_kernel(int* __restrict__ bsum, int* __restrict__ S,
                                 int B, int n) {
    __shared__ int sd[1024];
    int t = threadIdx.x;
    int v = (t < B) ? bsum[t] : 0;
    sd[t] = v;
    __syncthreads();
    for (int off = 1; off < 1024; off <<= 1) {
        int u = (t >= off) ? sd[t - off] : 0;
        __syncthreads();
        sd[t] = sd[t] + u;
        __syncthreads();
    }
    if (t < B) bsum[t] = sd[t] - v;
    if (t == 1023) S[n] = sd[1023];
}

__global__ void scan_write_kernel(const int* __restrict__ counts,
                                  const int* __restrict__ bsum,
                                  int* __restrict__ S, int* __restrict__ cursor,
                                  int n) {
    int b = blockIdx.x, t = threadIdx.x;
    int base = b * SCAN_CHUNK + t * 8;
    int v[8];
    int s = 0;
#pragma unroll
    for (int j = 0; j < 8; j++) {
        int i = base + j;
        v[j] = (i < n) ? counts[i] : 0;
        s += v[j];
    }
    __shared__ int sd[SCAN_BT];
    sd[t] = s;
    __syncthreads();
    for (int off = 1; off < SCAN_BT; off <<= 1) {
        int u = (t >= off) ? sd[t - off] : 0;
        __syncthreads();
        sd[t] = sd[t] + u;
        __syncthreads();
    }
    int run = bsum[b] + sd[t] - s;
#pragma unroll
    for (int j = 0; j < 8; j++) {
        int i = base + j;
        if (i < n) {
            S[i] = run;
            cursor[i] = run;
            run += v[j];
        }
    }
}

__global__ void fill_kernel(const int* __restrict__ src, const int* __restrict__ dst,
                            int* __restrict__ cursor, int* __restrict__ csr_src,
                            int E, int N) {
    int i = blockIdx.x * blockDim.x + threadIdx.x;
    if (i >= 2 * E) return;
    int r = (i >= E) ? 1 : 0;
    int pos = atomicAdd(&cursor[r * N + dst[i]], 1);
    csr_src[pos] = src[i];
}

// ---------------------------------------------------------------------------
// Owner-computes GAT aggregation: one 64-lane wave per destination node.
// ---------------------------------------------------------------------------
template <bool FIRST>
__launch_bounds__(256)
__global__ void gat_aggregate_kernel(const int* __restrict__ rowptr,
                                     const int* __restrict__ csrc,
                                     const float* __restrict__ el,
                                     const float* __restrict__ er,
                                     const float* __restrict__ feat,
                                     const float* __restrict__ ba,
                                     const float* __restrict__ bb,
                                     float* __restrict__ hout,
                                     int n) {
    int node = blockIdx.x * 4 + (threadIdx.x >> 6);
    if (node >= n) return;
    int lane = threadIdx.x & 63;
    int h = lane >> 5;

    int rs = rowptr[node], re = rowptr[node + 1];
    float er0 = er[node * 2], er1 = er[node * 2 + 1];

    float2 acc = make_float2(0.f, 0.f);
    float m0 = -INFINITY, m1 = -INFINITY;
    float den0 = 0.f, den1 = 0.f;
    const float2* feat2 = reinterpret_cast<const float2*>(feat);

    for (int base = rs; base < re; base += 64) {
        int c = re - base; if (c > 64) c = 64;
        int msrc = 0;
        float s0 = -INFINITY, s1 = -INFINITY;
        if (lane < c) {
            msrc = csrc[base + lane];
            float2 a = *reinterpret_cast<const float2*>(el + (size_t)msrc * 2);
            s0 = a.x + er0; s0 = s0 > 0.f ? s0 : 0.2f * s0;
            s1 = a.y + er1; s1 = s1 > 0.f ? s1 : 0.2f * s1;
        }
        float c0 = s0, c1 = s1;
#pragma unroll
        for (int msk = 32; msk >= 1; msk >>= 1) {
            c0 = fmaxf(c0, __shfl_xor(c0, msk));
            c1 = fmaxf(c1, __shfl_xor(c1, msk));
        }
        float mn0 = fmaxf(m0, c0), mn1 = fmaxf(m1, c1);
        float sc0 = __expf(m0 - mn0), sc1 = __expf(m1 - mn1);
        float ex0 = (lane < c) ? __expf(s0 - mn0) : 0.f;
        float ex1 = (lane < c) ? __expf(s1 - mn1) : 0.f;
        float t0 = ex0, t1 = ex1;
#pragma unroll
        for (int msk = 32; msk >= 1; msk >>= 1) {
            t0 += __shfl_xor(t0, msk);
            t1 += __shfl_xor(t1, msk);
        }
        den0 = den0 * sc0 + t0;
        den1 = den1 * sc1 + t1;
        float sch = (h == 0) ? sc0 : sc1;
        acc.x *= sch;
        acc.y *= sch;
        for (int j = 0; j < c; ++j) {
            int sj = __shfl(msrc, j);
            float a0 = __shfl(ex0, j);
            float a1 = __shfl(ex1, j);
            float a = (h == 0) ? a0 : a1;
            float2 f = feat2[(size_t)sj * 64 + lane];
            acc.x = fmaf(a, f.x, acc.x);
            acc.y = fmaf(a, f.y, acc.y);
        }
        m0 = mn0;
        m1 = mn1;
    }

    float den = (h == 0) ? den0 : den1;
    float invd = (den > 0.f) ? 1.f / den : 0.f;
    float2* o2 = reinterpret_cast<float2*>(hout) + (size_t)node * 64 + lane;
    float2 o;
    if (FIRST) {
        const float2* ba2 = reinterpret_cast<const float2*>(ba);
        const float2* bb2 = reinterpret_cast<const float2*>(bb);
        float2 b1v = ba2[lane], b2v = bb2[lane];
        o.x = b1v.x + b2v.x + acc.x * invd;
        o.y = b1v.y + b2v.y + acc.y * invd;
    } else {
        o = *o2;
        o.x += acc.x * invd;
        o.y += acc.y * invd;
    }
    *o2 = o;
}

// ---------------------------------------------------------------------------
// Hout (n x 64) = [relu]( Hin (n x 128) @ Wl (128 x 64) + bl )
// feat_gemm-style: 64 nodes/block, W in LDS (32 KB), float4 loads throughout.
// Thread t: cg = t&15 (4 cols), ng = t>>4 (4 nodes) -> 16 outputs/thread.
// ---------------------------------------------------------------------------
template <bool RELU>
__launch_bounds__(256)
__global__ void linear_kernel(const float* __restrict__ Hin, const float* __restrict__ Wl,
                              const float* __restrict__ bl, float* __restrict__ Hout, int n) {
    __shared__ float4 Wl4[128 * 16];  // 128 rows x 64 cols
    const int tid = threadIdx.x;
    const float4* W4 = reinterpret_cast<const float4*>(Wl);
    for (int i = tid; i < 128 * 16; i += 256) Wl4[i] = W4[i];
    __syncthreads();

    const int cg = tid & 15;   // column group (4 cols of 64)
    const int ng = tid >> 4;   // node subgroup 0..15
    const int n0 = blockIdx.x * 64 + ng * 4;

    const float4 bv = reinterpret_cast<const float4*>(bl)[cg];
    float4 acc[4];
#pragma unroll
    for (int i = 0; i < 4; i++) acc[i] = bv;

    const float4* X4 = reinterpret_cast<const float4*>(Hin);
    const float4* xrow[4];
#pragma unroll
    for (int i = 0; i < 4; i++) {
        int nn = n0 + i;
        int nc = nn < n ? nn : (n - 1);
        xrow[i] = X4 + (size_t)nc * 32;  // 128 floats = 32 float4
    }

    for (int k4 = 0; k4 < 32; ++k4) {
        float4 xv[4];
#pragma unroll
        for (int i = 0; i < 4; i++) xv[i] = xrow[i][k4];
#pragma unroll
        for (int j = 0; j < 4; j++) {
            float4 wv = Wl4[(k4 * 4 + j) * 16 + cg];
#pragma unroll
            for (int i = 0; i < 4; i++) {
                float xs = (j == 0) ? xv[i].x : (j == 1) ? xv[i].y : (j == 2) ? xv[i].z : xv[i].w;
                acc[i].x = fmaf(xs, wv.x, acc[i].x);
                acc[i].y = fmaf(xs, wv.y, acc[i].y);
                acc[i].z = fmaf(xs, wv.z, acc[i].z);
                acc[i].w = fmaf(xs, wv.w, acc[i].w);
            }
        }
    }

    float4* O4 = reinterpret_cast<float4*>(Hout);
#pragma unroll
    for (int i = 0; i < 4; i++) {
        int nn = n0 + i;
        if (nn < n) {
            float4 v = acc[i];
            if (RELU) {
                v.x = fmaxf(v.x, 0.f); v.y = fmaxf(v.y, 0.f);
                v.z = fmaxf(v.z, 0.f); v.w = fmaxf(v.w, 0.f);
            }
            O4[(size_t)nn * 16 + cg] = v;
        }
    }
}

// ---------------------------------------------------------------------------
extern "C" void kernel_launch(void* const* d_in, const int* in_sizes, int n_in,
                              void* d_out, int out_size, void* d_ws, size_t ws_size,
                              hipStream_t stream) {
    const float* x    = (const float*)d_in[0];
    const int*   src  = (const int*)d_in[1];
    const int*   dst  = (const int*)d_in[2];
    const float* W0   = (const float*)d_in[3];
    const float* al0  = (const float*)d_in[4];
    const float* ar0  = (const float*)d_in[5];
    const float* b0   = (const float*)d_in[6];
    const float* W1   = (const float*)d_in[7];
    const float* al1  = (const float*)d_in[8];
    const float* ar1  = (const float*)d_in[9];
    const float* b1   = (const float*)d_in[10];
    const float* linW0 = (const float*)d_in[11];
    const float* linb0 = (const float*)d_in[12];
    const float* linW1 = (const float*)d_in[13];
    const float* linb1 = (const float*)d_in[14];
    float* out = (float*)d_out;

    const int N = in_sizes[0] / IN_DIM;
    const int E = in_sizes[1] / R_REL;
    const int n2 = 2 * N;

    // workspace layout
    float* ws   = (float*)d_ws;
    float* feat = ws;                       // N*128
    float* hbuf = feat + (size_t)N * 128;   // N*128
    float* hmid = hbuf + (size_t)N * 128;   // N*64
    float* el   = hmid + (size_t)N * 64;    // N*2
    float* er   = el + (size_t)N * 2;       // N*2
    int* counts = (int*)(er + (size_t)N * 2);      // 2N
    int* S      = counts + (size_t)n2;             // 2N+1
    int* cursor = S + (size_t)(n2 + 1);            // 2N
    int* bsum   = cursor + (size_t)n2;             // up to 1024
    int* csrsrc = bsum + 1024;                     // 2E

    const int TB = 256;
    const int gemm_blocks = (N + 63) / 64;
    const int bagg = (N + 3) / 4;
    const int blin = (N + 63) / 64;
    const int b2n = (n2 + TB - 1) / TB;
    const int b2e = (2 * E + TB - 1) / TB;
    const int bscan = (n2 + SCAN_CHUNK - 1) / SCAN_CHUNK;

    // ---------------- CSR build (once; shared by both layers) -------------
    zero_counts_kernel<<<b2n, TB, 0, stream>>>(counts, n2);
    count_kernel<<<b2e, TB, 0, stream>>>(dst, counts, E, N);
    scan_blocksum_kernel<<<bscan, SCAN_BT, 0, stream>>>(counts, bsum, n2);
    scan_bsum_kernel<<<1, 1024, 0, stream>>>(bsum, S, bscan, n2);
    scan_write_kernel<<<bscan, SCAN_BT, 0, stream>>>(counts, bsum, S, cursor, n2);
    fill_kernel<<<b2e, TB, 0, stream>>>(src, dst, cursor, csrsrc, E, N);

    // ---------------- layer 0 ----------------
    for (int r = 0; r < R_REL; r++) {
        const float* Wr  = W0 + (size_t)r * IN_DIM * FCOLS;
        const float* alr = al0 + (size_t)r * FCOLS;
        const float* arr = ar0 + (size_t)r * FCOLS;
        feat_gemm_kernel<IN_DIM><<<gemm_blocks, TB, 0, stream>>>(x, Wr, alr, arr, feat, el, er, N);
        if (r == 0)
            gat_aggregate_kernel<true><<<bagg, TB, 0, stream>>>(
                S, csrsrc, el, er, feat, b0, b0 + 128, hbuf, N);
        else
            gat_aggregate_kernel<false><<<bagg, TB, 0, stream>>>(
                S + N, csrsrc, el, er, feat, nullptr, nullptr, hbuf, N);
    }
    linear_kernel<true><<<blin, TB, 0, stream>>>(hbuf, linW0, linb0, hmid, N);

    // ---------------- layer 1 ----------------
    for (int r = 0; r < R_REL; r++) {
        const float* Wr  = W1 + (size_t)r * HID_DIM * FCOLS;
        const float* alr = al1 + (size_t)r * FCOLS;
        const float* arr = ar1 + (size_t)r * FCOLS;
        feat_gemm_kernel<HID_DIM><<<gemm_blocks, TB, 0, stream>>>(hmid, Wr, alr, arr, feat, el, er, N);
        if (r == 0)
            gat_aggregate_kernel<true><<<bagg, TB, 0, stream>>>(
                S, csrsrc, el, er, feat, b1, b1 + 128, hbuf, N);
        else
            gat_aggregate_kernel<false><<<bagg, TB, 0, stream>>>(
                S + N, csrsrc, el, er, feat, nullptr, nullptr, hbuf, N);
    }
    linear_kernel<false><<<blin, TB, 0, stream>>>(hbuf, linW1, linb1, out, N);
}

// Round 5
// 798.668 us; speedup vs baseline: 8.1455x; 1.0747x over previous
//
#include <hip/hip_runtime.h>
#include <math.h>

// Problem constants (match reference)
#define R_REL 2
#define IN_DIM 128
#define HID_DIM 64
#define FCOLS 128

// ---------------------------------------------------------------------------
// feat = X (n x K) @ W (K x 128), plus el[n][h] = dot(feat[n,h,:], al[h,:]),
// er likewise. al/ar passed as flat 128 floats (H*D).
// ---------------------------------------------------------------------------
template <int K>
__launch_bounds__(256)
__global__ void feat_gemm_kernel(const float* __restrict__ X,
                                 const float* __restrict__ W,
                                 const float* __restrict__ alv,
                                 const float* __restrict__ arv,
                                 float* __restrict__ feat,
                                 float* __restrict__ el,
                                 float* __restrict__ er,
                                 int n) {
    __shared__ float4 Wl4[K * 32];
    const int tid = threadIdx.x;
    const float4* W4 = reinterpret_cast<const float4*>(W);
    for (int i = tid; i < K * 32; i += 256) Wl4[i] = W4[i];
    __syncthreads();

    const int cg = tid & 31;   // column group (4 cols)
    const int ng = tid >> 5;   // node subgroup 0..7
    const int n0 = blockIdx.x * 64 + ng * 8;

    float4 acc[8];
#pragma unroll
    for (int i = 0; i < 8; i++) acc[i] = make_float4(0.f, 0.f, 0.f, 0.f);

    const int KV = K / 4;
    const float4* X4 = reinterpret_cast<const float4*>(X);
    const float4* xrow[8];
#pragma unroll
    for (int i = 0; i < 8; i++) {
        int nn = n0 + i;
        int nc = nn < n ? nn : (n - 1);
        xrow[i] = X4 + (size_t)nc * KV;
    }

    for (int k4 = 0; k4 < KV; ++k4) {
        float4 xv[8];
#pragma unroll
        for (int i = 0; i < 8; i++) xv[i] = xrow[i][k4];
#pragma unroll
        for (int j = 0; j < 4; j++) {
            float4 wv = Wl4[(k4 * 4 + j) * 32 + cg];
#pragma unroll
            for (int i = 0; i < 8; i++) {
                float xs = (j == 0) ? xv[i].x : (j == 1) ? xv[i].y : (j == 2) ? xv[i].z : xv[i].w;
                acc[i].x = fmaf(xs, wv.x, acc[i].x);
                acc[i].y = fmaf(xs, wv.y, acc[i].y);
                acc[i].z = fmaf(xs, wv.z, acc[i].z);
                acc[i].w = fmaf(xs, wv.w, acc[i].w);
            }
        }
    }

    const float4 alq = reinterpret_cast<const float4*>(alv)[cg];
    const float4 arq = reinterpret_cast<const float4*>(arv)[cg];
    float4* F4 = reinterpret_cast<float4*>(feat);
#pragma unroll
    for (int i = 0; i < 8; i++) {
        int nn = n0 + i;
        float pel = acc[i].x * alq.x + acc[i].y * alq.y + acc[i].z * alq.z + acc[i].w * alq.w;
        float per = acc[i].x * arq.x + acc[i].y * arq.y + acc[i].z * arq.z + acc[i].w * arq.w;
#pragma unroll
        for (int msk = 8; msk >= 1; msk >>= 1) {
            pel += __shfl_xor(pel, msk);
            per += __shfl_xor(per, msk);
        }
        if (nn < n) {
            F4[(size_t)nn * 32 + cg] = acc[i];
            if ((cg & 15) == 0) {
                int h = cg >> 4;
                el[nn * 2 + h] = pel;
                er[nn * 2 + h] = per;
            }
        }
    }
}

// ---------------------------------------------------------------------------
// CSR build over the CONCATENATED relations, XCD-partitioned:
// key = r*N + dst in [0, 2N). Partition p = key / kpp (kpp = ceil(2N/8)).
// Grid = 8 * nchunk; block's de-facto XCD = blockIdx & 7 (round-robin
// dispatch). A block scans a full edge chunk but only touches counters /
// csrsrc positions in its own partition -> each cache line is written by
// exactly one XCD, eliminating cross-XCD partial-line writeback churn.
// Correctness does NOT depend on the blockIdx->XCD mapping.
// ---------------------------------------------------------------------------
#define EDGE_CHUNK 2048

__global__ void zero_counts_kernel(int* __restrict__ counts, int n) {
    int i = blockIdx.x * blockDim.x + threadIdx.x;
    if (i < n) counts[i] = 0;
}

__global__ void count_xcd_kernel(const int* __restrict__ dst,
                                 int* __restrict__ counts,
                                 int E, int N, int kpp) {
    int part = blockIdx.x & 7;
    int base = (blockIdx.x >> 3) * EDGE_CHUNK + threadIdx.x;
    int total = 2 * E;
#pragma unroll
    for (int j = 0; j < 8; j++) {
        int i = base + j * 256;
        if (i < total) {
            int key = ((i >= E) ? N : 0) + dst[i];
            if (key / kpp == part) atomicAdd(&counts[key], 1);
        }
    }
}

// 3-phase scan, CHUNK = 2048 elements per 256-thread block (8/thread).
#define SCAN_CHUNK 2048
#define SCAN_BT 256

__global__ void scan_blocksum_kernel(const int* __restrict__ counts,
                                     int* __restrict__ bsum, int n) {
    int b = blockIdx.x, t = threadIdx.x;
    int base = b * SCAN_CHUNK + t * 8;
    int s = 0;
#pragma unroll
    for (int j = 0; j < 8; j++) {
        int i = base + j;
        if (i < n) s += counts[i];
    }
    __shared__ int sd[SCAN_BT];
    sd[t] = s;
    __syncthreads();
    for (int off = SCAN_BT / 2; off > 0; off >>= 1) {
        if (t < off) sd[t] += sd[t + off];
        __syncthreads();
    }
    if (t == 0) bsum[b] = sd[0];
}

__global__ void scan_bsum_kernel(int* __restrict__ bsum, int* __restrict__ S,
                                 int B, int n) {
    __shared__ int sd[1024];
    int t = threadIdx.x;
    int v = (t < B) ? bsum[t] : 0;
    sd[t] = v;
    __syncthreads();
    for (int off = 1; off < 1024; off <<= 1) {
        int u = (t >= off) ? sd[t - off] : 0;
        __syncthreads();
        sd[t] = sd[t] + u;
        __syncthreads();
    }
    if (t < B) bsum[t] = sd[t] - v;
    if (t == 1023) S[n] = sd[1023];
}

__global__ void scan_write_kernel(const int* __restrict__ counts,
                                  const int* __restrict__ bsum,
                                  int* __restrict__ S, int* __restrict__ cursor,
                                  int n) {
    int b = blockIdx.x, t = threadIdx.x;
    int base = b * SCAN_CHUNK + t * 8;
    int v[8];
    int s = 0;
#pragma unroll
    for (int j = 0; j < 8; j++) {
        int i = base + j;
        v[j] = (i < n) ? counts[i] : 0;
        s += v[j];
    }
    __shared__ int sd[SCAN_BT];
    sd[t] = s;
    __syncthreads();
    for (int off = 1; off < SCAN_BT; off <<= 1) {
        int u = (t >= off) ? sd[t - off] : 0;
        __syncthreads();
        sd[t] = sd[t] + u;
        __syncthreads();
    }
    int run = bsum[b] + sd[t] - s;
#pragma unroll
    for (int j = 0; j < 8; j++) {
        int i = base + j;
        if (i < n) {
            S[i] = run;
            cursor[i] = run;
            run += v[j];
        }
    }
}

__global__ void fill_xcd_kernel(const int* __restrict__ src,
                                const int* __restrict__ dst,
                                int* __restrict__ cursor,
                                int* __restrict__ csr_src,
                                int E, int N, int kpp) {
    int part = blockIdx.x & 7;
    int base = (blockIdx.x >> 3) * EDGE_CHUNK + threadIdx.x;
    int total = 2 * E;
#pragma unroll
    for (int j = 0; j < 8; j++) {
        int i = base + j * 256;
        if (i < total) {
            int key = ((i >= E) ? N : 0) + dst[i];
            if (key / kpp == part) {
                int pos = atomicAdd(&cursor[key], 1);
                csr_src[pos] = src[i];
            }
        }
    }
}

// ---------------------------------------------------------------------------
// Owner-computes GAT aggregation: one 64-lane wave per destination node.
// ---------------------------------------------------------------------------
template <bool FIRST>
__launch_bounds__(256)
__global__ void gat_aggregate_kernel(const int* __restrict__ rowptr,
                                     const int* __restrict__ csrc,
                                     const float* __restrict__ el,
                                     const float* __restrict__ er,
                                     const float* __restrict__ feat,
                                     const float* __restrict__ ba,
                                     const float* __restrict__ bb,
                                     float* __restrict__ hout,
                                     int n) {
    int node = blockIdx.x * 4 + (threadIdx.x >> 6);
    if (node >= n) return;
    int lane = threadIdx.x & 63;
    int h = lane >> 5;

    int rs = rowptr[node], re = rowptr[node + 1];
    float er0 = er[node * 2], er1 = er[node * 2 + 1];

    float2 acc = make_float2(0.f, 0.f);
    float m0 = -INFINITY, m1 = -INFINITY;
    float den0 = 0.f, den1 = 0.f;
    const float2* feat2 = reinterpret_cast<const float2*>(feat);

    for (int base = rs; base < re; base += 64) {
        int c = re - base; if (c > 64) c = 64;
        int msrc = 0;
        float s0 = -INFINITY, s1 = -INFINITY;
        if (lane < c) {
            msrc = csrc[base + lane];
            float2 a = *reinterpret_cast<const float2*>(el + (size_t)msrc * 2);
            s0 = a.x + er0; s0 = s0 > 0.f ? s0 : 0.2f * s0;
            s1 = a.y + er1; s1 = s1 > 0.f ? s1 : 0.2f * s1;
        }
        float c0 = s0, c1 = s1;
#pragma unroll
        for (int msk = 32; msk >= 1; msk >>= 1) {
            c0 = fmaxf(c0, __shfl_xor(c0, msk));
            c1 = fmaxf(c1, __shfl_xor(c1, msk));
        }
        float mn0 = fmaxf(m0, c0), mn1 = fmaxf(m1, c1);
        float sc0 = __expf(m0 - mn0), sc1 = __expf(m1 - mn1);
        float ex0 = (lane < c) ? __expf(s0 - mn0) : 0.f;
        float ex1 = (lane < c) ? __expf(s1 - mn1) : 0.f;
        float t0 = ex0, t1 = ex1;
#pragma unroll
        for (int msk = 32; msk >= 1; msk >>= 1) {
            t0 += __shfl_xor(t0, msk);
            t1 += __shfl_xor(t1, msk);
        }
        den0 = den0 * sc0 + t0;
        den1 = den1 * sc1 + t1;
        float sch = (h == 0) ? sc0 : sc1;
        acc.x *= sch;
        acc.y *= sch;
        for (int j = 0; j < c; ++j) {
            int sj = __shfl(msrc, j);
            float a0 = __shfl(ex0, j);
            float a1 = __shfl(ex1, j);
            float a = (h == 0) ? a0 : a1;
            float2 f = feat2[(size_t)sj * 64 + lane];
            acc.x = fmaf(a, f.x, acc.x);
            acc.y = fmaf(a, f.y, acc.y);
        }
        m0 = mn0;
        m1 = mn1;
    }

    float den = (h == 0) ? den0 : den1;
    float invd = (den > 0.f) ? 1.f / den : 0.f;
    float2* o2 = reinterpret_cast<float2*>(hout) + (size_t)node * 64 + lane;
    float2 o;
    if (FIRST) {
        const float2* ba2 = reinterpret_cast<const float2*>(ba);
        const float2* bb2 = reinterpret_cast<const float2*>(bb);
        float2 b1v = ba2[lane], b2v = bb2[lane];
        o.x = b1v.x + b2v.x + acc.x * invd;
        o.y = b1v.y + b2v.y + acc.y * invd;
    } else {
        o = *o2;
        o.x += acc.x * invd;
        o.y += acc.y * invd;
    }
    *o2 = o;
}

// ---------------------------------------------------------------------------
// Hout (n x 64) = [relu]( Hin (n x 128) @ Wl (128 x 64) + bl )
// ---------------------------------------------------------------------------
template <bool RELU>
__launch_bounds__(256)
__global__ void linear_kernel(const float* __restrict__ Hin, const float* __restrict__ Wl,
                              const float* __restrict__ bl, float* __restrict__ Hout, int n) {
    __shared__ float4 Wl4[128 * 16];  // 128 rows x 64 cols
    const int tid = threadIdx.x;
    const float4* W4 = reinterpret_cast<const float4*>(Wl);
    for (int i = tid; i < 128 * 16; i += 256) Wl4[i] = W4[i];
    __syncthreads();

    const int cg = tid & 15;   // column group (4 cols of 64)
    const int ng = tid >> 4;   // node subgroup 0..15
    const int n0 = blockIdx.x * 64 + ng * 4;

    const float4 bv = reinterpret_cast<const float4*>(bl)[cg];
    float4 acc[4];
#pragma unroll
    for (int i = 0; i < 4; i++) acc[i] = bv;

    const float4* X4 = reinterpret_cast<const float4*>(Hin);
    const float4* xrow[4];
#pragma unroll
    for (int i = 0; i < 4; i++) {
        int nn = n0 + i;
        int nc = nn < n ? nn : (n - 1);
        xrow[i] = X4 + (size_t)nc * 32;
    }

    for (int k4 = 0; k4 < 32; ++k4) {
        float4 xv[4];
#pragma unroll
        for (int i = 0; i < 4; i++) xv[i] = xrow[i][k4];
#pragma unroll
        for (int j = 0; j < 4; j++) {
            float4 wv = Wl4[(k4 * 4 + j) * 16 + cg];
#pragma unroll
            for (int i = 0; i < 4; i++) {
                float xs = (j == 0) ? xv[i].x : (j == 1) ? xv[i].y : (j == 2) ? xv[i].z : xv[i].w;
                acc[i].x = fmaf(xs, wv.x, acc[i].x);
                acc[i].y = fmaf(xs, wv.y, acc[i].y);
                acc[i].z = fmaf(xs, wv.z, acc[i].z);
                acc[i].w = fmaf(xs, wv.w, acc[i].w);
            }
        }
    }

    float4* O4 = reinterpret_cast<float4*>(Hout);
#pragma unroll
    for (int i = 0; i < 4; i++) {
        int nn = n0 + i;
        if (nn < n) {
            float4 v = acc[i];
            if (RELU) {
                v.x = fmaxf(v.x, 0.f); v.y = fmaxf(v.y, 0.f);
                v.z = fmaxf(v.z, 0.f); v.w = fmaxf(v.w, 0.f);
            }
            O4[(size_t)nn * 16 + cg] = v;
        }
    }
}

// ---------------------------------------------------------------------------
extern "C" void kernel_launch(void* const* d_in, const int* in_sizes, int n_in,
                              void* d_out, int out_size, void* d_ws, size_t ws_size,
                              hipStream_t stream) {
    const float* x    = (const float*)d_in[0];
    const int*   src  = (const int*)d_in[1];
    const int*   dst  = (const int*)d_in[2];
    const float* W0   = (const float*)d_in[3];
    const float* al0  = (const float*)d_in[4];
    const float* ar0  = (const float*)d_in[5];
    const float* b0   = (const float*)d_in[6];
    const float* W1   = (const float*)d_in[7];
    const float* al1  = (const float*)d_in[8];
    const float* ar1  = (const float*)d_in[9];
    const float* b1   = (const float*)d_in[10];
    const float* linW0 = (const float*)d_in[11];
    const float* linb0 = (const float*)d_in[12];
    const float* linW1 = (const float*)d_in[13];
    const float* linb1 = (const float*)d_in[14];
    float* out = (float*)d_out;

    const int N = in_sizes[0] / IN_DIM;
    const int E = in_sizes[1] / R_REL;
    const int n2 = 2 * N;
    const int kpp = (n2 + 7) / 8;  // keys per XCD partition

    // workspace layout
    float* ws   = (float*)d_ws;
    float* feat = ws;                       // N*128
    float* hbuf = feat + (size_t)N * 128;   // N*128
    float* hmid = hbuf + (size_t)N * 128;   // N*64
    float* el   = hmid + (size_t)N * 64;    // N*2
    float* er   = el + (size_t)N * 2;       // N*2
    int* counts = (int*)(er + (size_t)N * 2);      // 2N
    int* S      = counts + (size_t)n2;             // 2N+1
    int* cursor = S + (size_t)(n2 + 1);            // 2N
    int* bsum   = cursor + (size_t)n2;             // up to 1024
    int* csrsrc = bsum + 1024;                     // 2E

    const int TB = 256;
    const int gemm_blocks = (N + 63) / 64;
    const int bagg = (N + 3) / 4;
    const int blin = (N + 63) / 64;
    const int b2n = (n2 + TB - 1) / TB;
    const int nchunk = (2 * E + EDGE_CHUNK - 1) / EDGE_CHUNK;
    const int bscan = (n2 + SCAN_CHUNK - 1) / SCAN_CHUNK;

    // ---------------- CSR build (once; shared by both layers) -------------
    zero_counts_kernel<<<b2n, TB, 0, stream>>>(counts, n2);
    count_xcd_kernel<<<nchunk * 8, TB, 0, stream>>>(dst, counts, E, N, kpp);
    scan_blocksum_kernel<<<bscan, SCAN_BT, 0, stream>>>(counts, bsum, n2);
    scan_bsum_kernel<<<1, 1024, 0, stream>>>(bsum, S, bscan, n2);
    scan_write_kernel<<<bscan, SCAN_BT, 0, stream>>>(counts, bsum, S, cursor, n2);
    fill_xcd_kernel<<<nchunk * 8, TB, 0, stream>>>(src, dst, cursor, csrsrc, E, N, kpp);

    // ---------------- layer 0 ----------------
    for (int r = 0; r < R_REL; r++) {
        const float* Wr  = W0 + (size_t)r * IN_DIM * FCOLS;
        const float* alr = al0 + (size_t)r * FCOLS;
        const float* arr = ar0 + (size_t)r * FCOLS;
        feat_gemm_kernel<IN_DIM><<<gemm_blocks, TB, 0, stream>>>(x, Wr, alr, arr, feat, el, er, N);
        if (r == 0)
            gat_aggregate_kernel<true><<<bagg, TB, 0, stream>>>(
                S, csrsrc, el, er, feat, b0, b0 + 128, hbuf, N);
        else
            gat_aggregate_kernel<false><<<bagg, TB, 0, stream>>>(
                S + N, csrsrc, el, er, feat, nullptr, nullptr, hbuf, N);
    }
    linear_kernel<true><<<blin, TB, 0, stream>>>(hbuf, linW0, linb0, hmid, N);

    // ---------------- layer 1 ----------------
    for (int r = 0; r < R_REL; r++) {
        const float* Wr  = W1 + (size_t)r * HID_DIM * FCOLS;
        const float* alr = al1 + (size_t)r * FCOLS;
        const float* arr = ar1 + (size_t)r * FCOLS;
        feat_gemm_kernel<HID_DIM><<<gemm_blocks, TB, 0, stream>>>(hmid, Wr, alr, arr, feat, el, er, N);
        if (r == 0)
            gat_aggregate_kernel<true><<<bagg, TB, 0, stream>>>(
                S, csrsrc, el, er, feat, b1, b1 + 128, hbuf, N);
        else
            gat_aggregate_kernel<false><<<bagg, TB, 0, stream>>>(
                S + N, csrsrc, el, er, feat, nullptr, nullptr, hbuf, N);
    }
    linear_kernel<false><<<blin, TB, 0, stream>>>(hbuf, linW1, linb1, out, N);
}